// Round 1
// baseline (329.528 us; speedup 1.0000x reference)
//
#include <hip/hip_runtime.h>
#include <math.h>

#define E_ 8
#define H_ 256
#define N_ 65536
#define NHID_ 3
#define MT 64          // tile: N/64 = 1024 exact
#define HPAD 264       // LDS row stride (bf16 elems): row stride 528B
#define OMEGA_ 30.0f
#define REV_SCALE 4.7746482927568605f   // OMEGA/(2*pi): sin(OMEGA*z) = sin(2pi*(REV_SCALE*z))

// R19: 32x32x16 MFMA for hidden layers (2382 vs 2075 TF), conflict-free epilogue
// stores (32x32 C-layout splits lanes 0-31 / 32-63 across disjoint 16-bank halves),
// e-loop fused into one block (grid 1024 = 4 blocks/CU exactly; out accumulated in
// regs -> no atomics, no zero kernel), Pwh_lo dropped (was never read on hot path).
// ws layout: Pwh_hi | Pwo_hi | Pwo_lo
#define PWH_ELEMS (E_ * NHID_ * 16 * 8 * 64 * 8)   // 1572864 bf16 = 3145728 B
#define PWO_ELEMS (E_ * 8 * 64 * 8)                // 32768 bf16 = 65536 B
#define WS_NEEDED ((size_t)PWH_ELEMS * 2 + 2 * (size_t)PWO_ELEMS * 2)  // 3276800 B

typedef __attribute__((ext_vector_type(8))) __bf16 bf16x8;
typedef __attribute__((ext_vector_type(4))) float f32x4;
typedef __attribute__((ext_vector_type(16))) float f32x16;

// RNE split (pack kernels + fallback path)
__device__ __forceinline__ void split_bf16(float v, __bf16& hi, __bf16& lo) {
  hi = (__bf16)v;
  lo = (__bf16)(v - (float)hi);
}

// hot-path: sin + RNE-bf16 + single LDS store
__device__ __forceinline__ void sin_store(float z_rev, __bf16* h_hi, int idx) {
  const float s = __builtin_amdgcn_sinf(__builtin_amdgcn_fractf(z_rev)); // sin(2*pi*z_rev)
  h_hi[idx] = (__bf16)s;   // RNE
}

// ---- zero d_out (fallback path only) ----
__global__ void zero_out_k(float* __restrict__ out) {
  out[blockIdx.x * 256 + threadIdx.x] = 0.0f;   // grid exactly N_*3/256
}

// ---- pack Wh*REV_SCALE -> bf16 hi, 32x32x16 B-fragment order ----
// frag linear index f = (el*16 + kb)*8 + ntg; elem (lane, j):
//   k = kb*16 + (lane>>5)*8 + j,  n = ntg*32 + (lane&31)
// threads = 24*16*8*64 = 196608 -> grid 768 x 256
__global__ void pack_wh_k(const float* __restrict__ Wh, __bf16* __restrict__ Phi) {
  int t = blockIdx.x * 256 + threadIdx.x;
  int lane = t & 63;
  int r = t >> 6;            // [0, 3072)
  int ntg = r & 7;
  int kb  = (r >> 3) & 15;
  int el  = r >> 7;          // [0, 24) = e*3+l
  int n   = ntg * 32 + (lane & 31);
  int k0  = kb * 16 + (lane >> 5) * 8;
  const float* src = Wh + (size_t)el * (H_ * H_);
  __bf16* dhi = Phi + (size_t)t * 8;
#pragma unroll
  for (int j = 0; j < 8; ++j)
    dhi[j] = (__bf16)(src[(size_t)(k0 + j) * H_ + n] * REV_SCALE);
}

// ---- pack Wout (UNscaled — final layer is linear), 16x16x32 layout ----
__global__ void pack_wout_k(const float* __restrict__ Wout,
                            __bf16* __restrict__ Phi, __bf16* __restrict__ Plo) {
  int t = blockIdx.x * 256 + threadIdx.x;   // 4096 threads -> grid 16 x 256
  int lane = t & 63;
  int kb = (t >> 6) & 7;
  int e  = t >> 9;
  int n  = lane & 15;
  int k0 = kb * 32 + (lane >> 4) * 8;
  __bf16* dhi = Phi + (size_t)t * 8;
  __bf16* dlo = Plo + (size_t)t * 8;
#pragma unroll
  for (int j = 0; j < 8; ++j) {
    float v = (n < 3) ? Wout[((size_t)e * H_ + (k0 + j)) * 3 + n] : 0.0f;
    __bf16 hi, lo;
    split_bf16(v, hi, lo);
    dhi[j] = hi; dlo[j] = lo;
  }
}

// ---- fused MoE-SIREN, PACKED path, MT=64, e-loop fused, 32x32x16 hidden GEMMs ----
// Wave w owns cols [64w, 64w+64) of the 64x256 tile as 2x2 tiles of 32x32.
// A-frag (32x32x16): row = lane&31 (+32*mt), k = kb*16 + (lane>>5)*8 + j
// B-frag:            col = lane&31 (+32*nt+64w), same k
// C/D (HW-verified): col = lane&31, row = (reg&3) + 8*(reg>>2) + 4*(lane>>5)
__global__ __launch_bounds__(256, 4) void moe_main_packed_k(
    const float* __restrict__ x,
    const float* __restrict__ gate_W,
    const float* __restrict__ gate_b,
    const float* __restrict__ W0,
    const float* __restrict__ b0,
    const __bf16* __restrict__ Pwh_hi,
    const float* __restrict__ bh,
    const __bf16* __restrict__ Pwo_hi,
    const __bf16* __restrict__ Pwo_lo,
    const float* __restrict__ bout,
    float* __restrict__ out)
{
  __shared__ alignas(16) __bf16 h_hi[MT * HPAD];   // 33792 B
  __shared__ float gate_all[MT][E_];               // 2048 B -> total 35840 B, 4 blocks/CU

  const int m0   = blockIdx.x * MT;
  const int tid  = threadIdx.x;
  const int wave = tid >> 6;
  const int lane = tid & 63;
  const int l15  = lane & 15;
  const int l31  = lane & 31;
  const int quad = lane >> 4;
  const int half = lane >> 5;

  // gate for ALL experts, once (fp32, matches jax softmax)
  if (tid < MT) {
    const int mg = m0 + tid;
    const float x0 = x[mg * 2 + 0];
    const float x1 = x[mg * 2 + 1];
    float lg[E_];
    float mx = -1e30f;
#pragma unroll
    for (int k = 0; k < E_; ++k) {
      lg[k] = x0 * gate_W[k] + x1 * gate_W[E_ + k] + gate_b[k];
      mx = fmaxf(mx, lg[k]);
    }
    float s = 0.0f;
#pragma unroll
    for (int k = 0; k < E_; ++k) s += __expf(lg[k] - mx);
    const float inv = 1.0f / s;
#pragma unroll
    for (int k = 0; k < E_; ++k) gate_all[tid][k] = __expf(lg[k] - mx) * inv;
  }

  float oacc[4] = {0.0f, 0.0f, 0.0f, 0.0f};

  const int ntg0 = wave * 2;
  const int abase = l31 * HPAD + half * 8;   // A-frag lane base into h_hi

#pragma unroll 1
  for (int e = 0; e < E_; ++e) {
    // protect h_hi from previous e's output-stage reads; also publishes gate_all (e=0)
    __syncthreads();

    // first sine layer fp32, omega/2pi folded; thread tid owns column n=tid, all 64 rows
    {
      const float w0a = W0[(e * 2 + 0) * H_ + tid] * REV_SCALE;
      const float w1a = W0[(e * 2 + 1) * H_ + tid] * REV_SCALE;
      const float bb  = b0[e * H_ + tid] * REV_SCALE;
      for (int m = 0; m < MT; ++m) {
        const float x0 = x[(m0 + m) * 2 + 0];
        const float x1 = x[(m0 + m) * 2 + 1];
        const float z_rev = fmaf(x1, w1a, fmaf(x0, w0a, bb));
        sin_store(z_rev, h_hi, m * HPAD + tid);
      }
    }
    __syncthreads();

#pragma unroll 1
    for (int l = 0; l < NHID_; ++l) {
      const int el = e * NHID_ + l;
      const __bf16* pB = Pwh_hi + ((size_t)(el * 16) * 8 + ntg0) * 512 + (size_t)lane * 8;
      const float* bhrow = bh + (size_t)el * H_;

      // bias folded into acc init (C/D col = lane-only -> one bias per nt, all 16 regs)
      float bias_rev[2];
#pragma unroll
      for (int nt = 0; nt < 2; ++nt)
        bias_rev[nt] = bhrow[wave * 64 + nt * 32 + l31] * REV_SCALE;

      f32x16 acc[2][2];
#pragma unroll
      for (int mt = 0; mt < 2; ++mt)
#pragma unroll
        for (int nt = 0; nt < 2; ++nt)
#pragma unroll
          for (int i = 0; i < 16; ++i)
            acc[mt][nt][i] = bias_rev[nt];

#pragma unroll 2
      for (int kb = 0; kb < 16; ++kb) {
        bf16x8 bf0 = *reinterpret_cast<const bf16x8*>(pB);
        bf16x8 bf1 = *reinterpret_cast<const bf16x8*>(pB + 512);
        pB += 8 * 512;   // next kb: frag index +8
        bf16x8 ah0 = *reinterpret_cast<const bf16x8*>(&h_hi[abase + kb * 16]);
        bf16x8 ah1 = *reinterpret_cast<const bf16x8*>(&h_hi[abase + 32 * HPAD + kb * 16]);
        acc[0][0] = __builtin_amdgcn_mfma_f32_32x32x16_bf16(ah0, bf0, acc[0][0], 0, 0, 0);
        acc[0][1] = __builtin_amdgcn_mfma_f32_32x32x16_bf16(ah0, bf1, acc[0][1], 0, 0, 0);
        acc[1][0] = __builtin_amdgcn_mfma_f32_32x32x16_bf16(ah1, bf0, acc[1][0], 0, 0, 0);
        acc[1][1] = __builtin_amdgcn_mfma_f32_32x32x16_bf16(ah1, bf1, acc[1][1], 0, 0, 0);
      }
      __syncthreads();

      // epilogue: sin + store. lanes 0-31 and 32-63 hit disjoint 16-bank halves
#pragma unroll
      for (int nt = 0; nt < 2; ++nt) {
        const int n = wave * 64 + nt * 32 + l31;
#pragma unroll
        for (int mt = 0; mt < 2; ++mt) {
          const int rb = mt * 32 + half * 4;
#pragma unroll
          for (int reg = 0; reg < 16; ++reg) {
            const int row = rb + (reg & 3) + 8 * (reg >> 2);
            sin_store(acc[mt][nt][reg], h_hi, row * HPAD + n);
          }
        }
      }
      __syncthreads();
    }

    // output layer (linear, 16x16x32, hi+lo kept — only 16 MFMAs/wave, free accuracy)
    {
      const __bf16* pOh = Pwo_hi + (size_t)e * (8 * 64 * 8) + (size_t)lane * 8;
      const __bf16* pOl = Pwo_lo + (size_t)e * (8 * 64 * 8) + (size_t)lane * 8;
      f32x4 acco = (f32x4){0.f, 0.f, 0.f, 0.f};
      const int arow = wave * 16 + l15;
#pragma unroll 1
      for (int kb = 0; kb < 8; ++kb) {
        bf16x8 bhf = *reinterpret_cast<const bf16x8*>(pOh);
        bf16x8 blf = *reinterpret_cast<const bf16x8*>(pOl);
        pOh += 512; pOl += 512;
        const int k0 = kb * 32 + quad * 8;
        bf16x8 ah = *reinterpret_cast<const bf16x8*>(&h_hi[arow * HPAD + k0]);
        acco = __builtin_amdgcn_mfma_f32_16x16x32_bf16(ah, blf, acco, 0, 0, 0);
        acco = __builtin_amdgcn_mfma_f32_16x16x32_bf16(ah, bhf, acco, 0, 0, 0);
      }
      const float bo = (l15 < 3) ? bout[e * 3 + l15] : 0.0f;
#pragma unroll
      for (int i = 0; i < 4; ++i) {
        const int m = wave * 16 + quad * 4 + i;
        oacc[i] = fmaf(gate_all[m][e], acco[i] + bo, oacc[i]);
      }
    }
  }

  // final store — no atomics, every (m, c<3) written exactly once
  if (l15 < 3) {
#pragma unroll
    for (int i = 0; i < 4; ++i) {
      const int m = wave * 16 + quad * 4 + i;
      out[(size_t)(m0 + m) * 3 + l15] = oacc[i];
    }
  }
}

// ---- fallback: direct fp32-weight path (HW-verified round 3, MT=64, 3-term) ----
__global__ __launch_bounds__(256) void moe_main_direct_k(
    const float* __restrict__ x,
    const float* __restrict__ gate_W,
    const float* __restrict__ gate_b,
    const float* __restrict__ W0,
    const float* __restrict__ b0,
    const float* __restrict__ Wh,
    const float* __restrict__ bh,
    const float* __restrict__ Wout,
    const float* __restrict__ bout,
    float* __restrict__ out)
{
  __shared__ alignas(16) __bf16 h_hi[MT * HPAD];
  __shared__ alignas(16) __bf16 h_lo[MT * HPAD];
  __shared__ float gate_s[MT];

  const int e    = blockIdx.y;
  const int m0   = blockIdx.x * MT;
  const int tid  = threadIdx.x;
  const int wave = tid >> 6;
  const int lane = tid & 63;
  const int l15  = lane & 15;
  const int quad = lane >> 4;

  if (tid < MT) {
    const int mg = m0 + tid;
    const float x0 = x[mg * 2 + 0];
    const float x1 = x[mg * 2 + 1];
    float lg[E_];
    float mx = -1e30f;
#pragma unroll
    for (int k = 0; k < E_; ++k) {
      lg[k] = x0 * gate_W[k] + x1 * gate_W[E_ + k] + gate_b[k];
      mx = fmaxf(mx, lg[k]);
    }
    float s = 0.0f;
#pragma unroll
    for (int k = 0; k < E_; ++k) s += __expf(lg[k] - mx);
    gate_s[tid] = __expf(lg[e] - mx) / s;
  }
  {
    const float w0a = W0[(e * 2 + 0) * H_ + tid];
    const float w1a = W0[(e * 2 + 1) * H_ + tid];
    const float bb  = b0[e * H_ + tid];
    for (int m = 0; m < MT; ++m) {
      const float x0 = x[(m0 + m) * 2 + 0];
      const float x1 = x[(m0 + m) * 2 + 1];
      const float z = OMEGA_ * fmaf(x1, w1a, fmaf(x0, w0a, bb));
      const float h = __sinf(z);
      __bf16 hi, lo; split_bf16(h, hi, lo);
      h_hi[m * HPAD + tid] = hi;
      h_lo[m * HPAD + tid] = lo;
    }
  }
  __syncthreads();

  const int nb0 = wave * 4;
#pragma unroll 1
  for (int l = 0; l < NHID_; ++l) {
    const float* WB = Wh + (size_t)(e * NHID_ + l) * (H_ * H_);
    f32x4 acc[4][4];
#pragma unroll
    for (int mt = 0; mt < 4; ++mt)
#pragma unroll
      for (int nbi = 0; nbi < 4; ++nbi)
        acc[mt][nbi] = (f32x4){0.f, 0.f, 0.f, 0.f};

#pragma unroll 2
    for (int kb = 0; kb < 8; ++kb) {
      const int k0 = kb * 32 + quad * 8;
      float bfv[4][8];
#pragma unroll
      for (int nbi = 0; nbi < 4; ++nbi) {
        const float* p = WB + (size_t)k0 * H_ + (nb0 + nbi) * 16 + l15;
#pragma unroll
        for (int j = 0; j < 8; ++j) bfv[nbi][j] = p[(size_t)j * H_];
      }
      bf16x8 ah[4], al[4];
#pragma unroll
      for (int mt = 0; mt < 4; ++mt) {
        ah[mt] = *reinterpret_cast<const bf16x8*>(&h_hi[(mt * 16 + l15) * HPAD + k0]);
        al[mt] = *reinterpret_cast<const bf16x8*>(&h_lo[(mt * 16 + l15) * HPAD + k0]);
      }
      bf16x8 bhf[4], blf[4];
#pragma unroll
      for (int nbi = 0; nbi < 4; ++nbi)
#pragma unroll
        for (int j = 0; j < 8; ++j) {
          __bf16 hi, lo; split_bf16(bfv[nbi][j], hi, lo);
          bhf[nbi][j] = hi; blf[nbi][j] = lo;
        }
#pragma unroll
      for (int mt = 0; mt < 4; ++mt)
#pragma unroll
        for (int nbi = 0; nbi < 4; ++nbi) {
          f32x4 a = acc[mt][nbi];
          a = __builtin_amdgcn_mfma_f32_16x16x32_bf16(al[mt], bhf[nbi], a, 0, 0, 0);
          a = __builtin_amdgcn_mfma_f32_16x16x32_bf16(ah[mt], blf[nbi], a, 0, 0, 0);
          a = __builtin_amdgcn_mfma_f32_16x16x32_bf16(ah[mt], bhf[nbi], a, 0, 0, 0);
          acc[mt][nbi] = a;
        }
    }
    __syncthreads();

    const float* bhrow = bh + (size_t)(e * NHID_ + l) * H_;
#pragma unroll
    for (int nbi = 0; nbi < 4; ++nbi) {
      const int n = (nb0 + nbi) * 16 + l15;
      const float bias = bhrow[n];
#pragma unroll
      for (int mt = 0; mt < 4; ++mt) {
        const int rbase = mt * 16 + quad * 4;
#pragma unroll
        for (int i = 0; i < 4; ++i) {
          const float z = OMEGA_ * (acc[mt][nbi][i] + bias);
          const float h = __sinf(z);
          __bf16 hi, lo; split_bf16(h, hi, lo);
          h_hi[(rbase + i) * HPAD + n] = hi;
          h_lo[(rbase + i) * HPAD + n] = lo;
        }
      }
    }
    __syncthreads();
  }

  {
    const float* WO = Wout + (size_t)e * (H_ * 3);
    f32x4 acco = (f32x4){0.f, 0.f, 0.f, 0.f};
    const int arow = wave * 16 + l15;
#pragma unroll
    for (int kb = 0; kb < 8; ++kb) {
      const int k0 = kb * 32 + quad * 8;
      float bfv[8];
#pragma unroll
      for (int j = 0; j < 8; ++j)
        bfv[j] = (l15 < 3) ? WO[(size_t)(k0 + j) * 3 + l15] : 0.0f;
      bf16x8 ah = *reinterpret_cast<const bf16x8*>(&h_hi[arow * HPAD + k0]);
      bf16x8 al = *reinterpret_cast<const bf16x8*>(&h_lo[arow * HPAD + k0]);
      bf16x8 bhf, blf;
#pragma unroll
      for (int j = 0; j < 8; ++j) {
        __bf16 hi, lo; split_bf16(bfv[j], hi, lo);
        bhf[j] = hi; blf[j] = lo;
      }
      acco = __builtin_amdgcn_mfma_f32_16x16x32_bf16(al, bhf, acco, 0, 0, 0);
      acco = __builtin_amdgcn_mfma_f32_16x16x32_bf16(ah, blf, acco, 0, 0, 0);
      acco = __builtin_amdgcn_mfma_f32_16x16x32_bf16(ah, bhf, acco, 0, 0, 0);
    }
    if (l15 < 3) {
      const float bo = bout[e * 3 + l15];
      const int rb = wave * 16 + quad * 4;
#pragma unroll
      for (int i = 0; i < 4; ++i) {
        const int m = rb + i;
        const float val = gate_s[m] * (acco[i] + bo);
        atomicAdd(&out[(size_t)(m0 + m) * 3 + l15], val);
      }
    }
  }
}

extern "C" void kernel_launch(void* const* d_in, const int* in_sizes, int n_in,
                              void* d_out, int out_size, void* d_ws, size_t ws_size,
                              hipStream_t stream) {
  const float* x     = (const float*)d_in[0];
  const float* gateW = (const float*)d_in[1];
  const float* gateb = (const float*)d_in[2];
  const float* W0    = (const float*)d_in[3];
  const float* b0    = (const float*)d_in[4];
  const float* Wh    = (const float*)d_in[5];
  const float* bh    = (const float*)d_in[6];
  const float* Wout  = (const float*)d_in[7];
  const float* bout  = (const float*)d_in[8];
  float* out = (float*)d_out;

  if (ws_size >= WS_NEEDED) {
    __bf16* Pwh_hi = (__bf16*)d_ws;
    __bf16* Pwo_hi = (__bf16*)((char*)d_ws + (size_t)PWH_ELEMS * 2);
    __bf16* Pwo_lo = (__bf16*)((char*)d_ws + (size_t)PWH_ELEMS * 2 + (size_t)PWO_ELEMS * 2);
    hipLaunchKernelGGL(pack_wh_k,  dim3(768), dim3(256), 0, stream, Wh, Pwh_hi);
    hipLaunchKernelGGL(pack_wout_k, dim3(16), dim3(256), 0, stream, Wout, Pwo_hi, Pwo_lo);
    hipLaunchKernelGGL(moe_main_packed_k, dim3(N_ / MT), dim3(256), 0, stream,
                       x, gateW, gateb, W0, b0, Pwh_hi, bh, Pwo_hi, Pwo_lo, bout, out);
  } else {
    hipLaunchKernelGGL(zero_out_k, dim3(N_ * 3 / 256), dim3(256), 0, stream, out);
    hipLaunchKernelGGL(moe_main_direct_k, dim3(N_ / MT, E_), dim3(256), 0, stream,
                       x, gateW, gateb, W0, b0, Wh, bh, Wout, bout, out);
  }
}

// Round 2
// 318.780 us; speedup vs baseline: 1.0337x; 1.0337x over previous
//
#include <hip/hip_runtime.h>
#include <math.h>

#define E_ 8
#define H_ 256
#define N_ 65536
#define NHID_ 3
#define MT 64          // tile: N/64 = 1024 exact
#define HPAD 264       // LDS row stride (bf16 elems): row stride 528B
#define OMEGA_ 30.0f
#define REV_SCALE 4.7746482927568605f   // OMEGA/(2*pi): sin(OMEGA*z) = sin(2pi*(REV_SCALE*z))

// R20: R18's per-expert grid (1024x8 blocks -> continuous block re-dispatch keeps
// CU-resident blocks phase-staggered; R18 measured MfmaUtil+VALUBusy=97%) with
// R19's verified per-op wins grafted on:
//   - 32x32x16 hidden GEMMs (2382 vs 2075 TF ceiling, half the MFMA instructions)
//   - conflict-free 32x32 epilogue stores (R19 measured: conflicts 13.6M -> 1.33M)
//   - bias folded into acc init
//   - single-plane Wh pack (lo plane was never read on hot path)
// R19's e-fusion (grid 1024, one aligned residency set) exposed ~72us of idle:
// MfmaUtil+VALUBusy fell to 74% because all 4 blocks/CU hit barriers in lockstep.
// ws layout: Pwh_hi | Pwo_hi | Pwo_lo
#define PWH_ELEMS (E_ * NHID_ * 16 * 8 * 64 * 8)   // 1572864 bf16 = 3145728 B
#define PWO_ELEMS (E_ * 8 * 64 * 8)                // 32768 bf16 = 65536 B
#define WS_NEEDED ((size_t)PWH_ELEMS * 2 + 2 * (size_t)PWO_ELEMS * 2)  // 3276800 B

typedef __attribute__((ext_vector_type(8))) __bf16 bf16x8;
typedef __attribute__((ext_vector_type(4))) float f32x4;
typedef __attribute__((ext_vector_type(16))) float f32x16;

// RNE split (pack kernels + fallback path)
__device__ __forceinline__ void split_bf16(float v, __bf16& hi, __bf16& lo) {
  hi = (__bf16)v;
  lo = (__bf16)(v - (float)hi);
}

// hot-path: sin + RNE-bf16 + single LDS store
__device__ __forceinline__ void sin_store(float z_rev, __bf16* h_hi, int idx) {
  const float s = __builtin_amdgcn_sinf(__builtin_amdgcn_fractf(z_rev)); // sin(2*pi*z_rev)
  h_hi[idx] = (__bf16)s;   // RNE
}

// ---- zero d_out ----
__global__ void zero_out_k(float* __restrict__ out) {
  out[blockIdx.x * 256 + threadIdx.x] = 0.0f;   // grid exactly N_*3/256
}

// ---- pack Wh*REV_SCALE -> bf16 hi, 32x32x16 B-fragment order ----
// frag linear index f = (el*16 + kb)*8 + ntg; elem (lane, j):
//   k = kb*16 + (lane>>5)*8 + j,  n = ntg*32 + (lane&31)
// threads = 24*16*8*64 = 196608 -> grid 768 x 256
__global__ void pack_wh_k(const float* __restrict__ Wh, __bf16* __restrict__ Phi) {
  int t = blockIdx.x * 256 + threadIdx.x;
  int lane = t & 63;
  int r = t >> 6;            // [0, 3072)
  int ntg = r & 7;
  int kb  = (r >> 3) & 15;
  int el  = r >> 7;          // [0, 24) = e*3+l
  int n   = ntg * 32 + (lane & 31);
  int k0  = kb * 16 + (lane >> 5) * 8;
  const float* src = Wh + (size_t)el * (H_ * H_);
  __bf16* dhi = Phi + (size_t)t * 8;
#pragma unroll
  for (int j = 0; j < 8; ++j)
    dhi[j] = (__bf16)(src[(size_t)(k0 + j) * H_ + n] * REV_SCALE);
}

// ---- pack Wout (UNscaled — final layer is linear), 16x16x32 layout ----
__global__ void pack_wout_k(const float* __restrict__ Wout,
                            __bf16* __restrict__ Phi, __bf16* __restrict__ Plo) {
  int t = blockIdx.x * 256 + threadIdx.x;   // 4096 threads -> grid 16 x 256
  int lane = t & 63;
  int kb = (t >> 6) & 7;
  int e  = t >> 9;
  int n  = lane & 15;
  int k0 = kb * 32 + (lane >> 4) * 8;
  __bf16* dhi = Phi + (size_t)t * 8;
  __bf16* dlo = Plo + (size_t)t * 8;
#pragma unroll
  for (int j = 0; j < 8; ++j) {
    float v = (n < 3) ? Wout[((size_t)e * H_ + (k0 + j)) * 3 + n] : 0.0f;
    __bf16 hi, lo;
    split_bf16(v, hi, lo);
    dhi[j] = hi; dlo[j] = lo;
  }
}

// ---- fused MoE-SIREN, PACKED path, MT=64, per-expert blocks, 32x32x16 GEMMs ----
// Wave w owns cols [64w, 64w+64) of the 64x256 tile as 2x2 tiles of 32x32.
// A-frag (32x32x16): row = lane&31 (+32*mt), k = kb*16 + (lane>>5)*8 + j
// B-frag:            col = lane&31 (+32*nt+64w), same k
// C/D (HW-verified): col = lane&31, row = (reg&3) + 8*(reg>>2) + 4*(lane>>5)
__global__ __launch_bounds__(256, 4) void moe_main_packed_k(
    const float* __restrict__ x,
    const float* __restrict__ gate_W,
    const float* __restrict__ gate_b,
    const float* __restrict__ W0,
    const float* __restrict__ b0,
    const __bf16* __restrict__ Pwh_hi,
    const float* __restrict__ bh,
    const __bf16* __restrict__ Pwo_hi,
    const __bf16* __restrict__ Pwo_lo,
    const float* __restrict__ bout,
    float* __restrict__ out)
{
  __shared__ alignas(16) __bf16 h_hi[MT * HPAD];   // 33792 B
  __shared__ float gate_s[MT];                     // total ~34 KB -> 4 blocks/CU

  const int e    = blockIdx.y;
  const int m0   = blockIdx.x * MT;
  const int tid  = threadIdx.x;
  const int wave = tid >> 6;
  const int lane = tid & 63;
  const int l15  = lane & 15;
  const int l31  = lane & 31;
  const int quad = lane >> 4;
  const int half = lane >> 5;

  // gate for this expert, one row per thread (fp32, matches jax softmax)
  if (tid < MT) {
    const int mg = m0 + tid;
    const float x0 = x[mg * 2 + 0];
    const float x1 = x[mg * 2 + 1];
    float lg[E_];
    float mx = -1e30f;
#pragma unroll
    for (int k = 0; k < E_; ++k) {
      lg[k] = x0 * gate_W[k] + x1 * gate_W[E_ + k] + gate_b[k];
      mx = fmaxf(mx, lg[k]);
    }
    float s = 0.0f;
#pragma unroll
    for (int k = 0; k < E_; ++k) s += __expf(lg[k] - mx);
    gate_s[tid] = __expf(lg[e] - mx) / s;
  }

  // first sine layer fp32, omega/2pi folded; thread tid owns column n=tid, all 64 rows
  {
    const float w0a = W0[(e * 2 + 0) * H_ + tid] * REV_SCALE;
    const float w1a = W0[(e * 2 + 1) * H_ + tid] * REV_SCALE;
    const float bb  = b0[e * H_ + tid] * REV_SCALE;
    for (int m = 0; m < MT; ++m) {
      const float x0 = x[(m0 + m) * 2 + 0];
      const float x1 = x[(m0 + m) * 2 + 1];
      const float z_rev = fmaf(x1, w1a, fmaf(x0, w0a, bb));
      sin_store(z_rev, h_hi, m * HPAD + tid);
    }
  }
  __syncthreads();

  const int ntg0 = wave * 2;
  const int abase = l31 * HPAD + half * 8;   // A-frag lane base into h_hi

#pragma unroll 1
  for (int l = 0; l < NHID_; ++l) {
    const int el = e * NHID_ + l;
    const __bf16* pB = Pwh_hi + ((size_t)(el * 16) * 8 + ntg0) * 512 + (size_t)lane * 8;
    const float* bhrow = bh + (size_t)el * H_;

    // bias folded into acc init (C/D col = lane-only -> one bias per nt, all 16 regs)
    float bias_rev[2];
#pragma unroll
    for (int nt = 0; nt < 2; ++nt)
      bias_rev[nt] = bhrow[wave * 64 + nt * 32 + l31] * REV_SCALE;

    f32x16 acc[2][2];
#pragma unroll
    for (int mt = 0; mt < 2; ++mt)
#pragma unroll
      for (int nt = 0; nt < 2; ++nt)
#pragma unroll
        for (int i = 0; i < 16; ++i)
          acc[mt][nt][i] = bias_rev[nt];

#pragma unroll 2
    for (int kb = 0; kb < 16; ++kb) {
      bf16x8 bf0 = *reinterpret_cast<const bf16x8*>(pB);
      bf16x8 bf1 = *reinterpret_cast<const bf16x8*>(pB + 512);
      pB += 8 * 512;   // next kb: frag index +8
      bf16x8 ah0 = *reinterpret_cast<const bf16x8*>(&h_hi[abase + kb * 16]);
      bf16x8 ah1 = *reinterpret_cast<const bf16x8*>(&h_hi[abase + 32 * HPAD + kb * 16]);
      acc[0][0] = __builtin_amdgcn_mfma_f32_32x32x16_bf16(ah0, bf0, acc[0][0], 0, 0, 0);
      acc[0][1] = __builtin_amdgcn_mfma_f32_32x32x16_bf16(ah0, bf1, acc[0][1], 0, 0, 0);
      acc[1][0] = __builtin_amdgcn_mfma_f32_32x32x16_bf16(ah1, bf0, acc[1][0], 0, 0, 0);
      acc[1][1] = __builtin_amdgcn_mfma_f32_32x32x16_bf16(ah1, bf1, acc[1][1], 0, 0, 0);
    }
    __syncthreads();

    // epilogue: sin + store. lanes 0-31 and 32-63 hit disjoint 16-bank halves
    // (row offset 4*HPAD = 2112 B == 16 banks); within a half, 32 lanes span
    // 64 contiguous bytes = 16 banks at 2 lanes/bank (free).
#pragma unroll
    for (int nt = 0; nt < 2; ++nt) {
      const int n = wave * 64 + nt * 32 + l31;
#pragma unroll
      for (int mt = 0; mt < 2; ++mt) {
        const int rb = mt * 32 + half * 4;
#pragma unroll
        for (int reg = 0; reg < 16; ++reg) {
          const int row = rb + (reg & 3) + 8 * (reg >> 2);
          sin_store(acc[mt][nt][reg], h_hi, row * HPAD + n);
        }
      }
    }
    __syncthreads();
  }

  // output layer (linear): 2-term kept (only 16 MFMAs/wave — free accuracy)
  {
    const __bf16* pOh = Pwo_hi + (size_t)e * (8 * 64 * 8) + (size_t)lane * 8;
    const __bf16* pOl = Pwo_lo + (size_t)e * (8 * 64 * 8) + (size_t)lane * 8;
    f32x4 acco = (f32x4){0.f, 0.f, 0.f, 0.f};
    const int arow = wave * 16 + l15;
#pragma unroll 1
    for (int kb = 0; kb < 8; ++kb) {
      bf16x8 bhf = *reinterpret_cast<const bf16x8*>(pOh);
      bf16x8 blf = *reinterpret_cast<const bf16x8*>(pOl);
      pOh += 512; pOl += 512;
      const int k0 = kb * 32 + quad * 8;
      bf16x8 ah = *reinterpret_cast<const bf16x8*>(&h_hi[arow * HPAD + k0]);
      acco = __builtin_amdgcn_mfma_f32_16x16x32_bf16(ah, blf, acco, 0, 0, 0);
      acco = __builtin_amdgcn_mfma_f32_16x16x32_bf16(ah, bhf, acco, 0, 0, 0);
    }
    if (l15 < 3) {
      const float bo = bout[e * 3 + l15];
      const int rb = wave * 16 + quad * 4;
#pragma unroll
      for (int i = 0; i < 4; ++i) {
        const int m = rb + i;
        const float val = gate_s[m] * (acco[i] + bo);
        atomicAdd(&out[(size_t)(m0 + m) * 3 + l15], val);
      }
    }
  }
}

// ---- fallback: direct fp32-weight path (HW-verified round 3, MT=64, 3-term) ----
__global__ __launch_bounds__(256) void moe_main_direct_k(
    const float* __restrict__ x,
    const float* __restrict__ gate_W,
    const float* __restrict__ gate_b,
    const float* __restrict__ W0,
    const float* __restrict__ b0,
    const float* __restrict__ Wh,
    const float* __restrict__ bh,
    const float* __restrict__ Wout,
    const float* __restrict__ bout,
    float* __restrict__ out)
{
  __shared__ alignas(16) __bf16 h_hi[MT * HPAD];
  __shared__ alignas(16) __bf16 h_lo[MT * HPAD];
  __shared__ float gate_s[MT];

  const int e    = blockIdx.y;
  const int m0   = blockIdx.x * MT;
  const int tid  = threadIdx.x;
  const int wave = tid >> 6;
  const int lane = tid & 63;
  const int l15  = lane & 15;
  const int quad = lane >> 4;

  if (tid < MT) {
    const int mg = m0 + tid;
    const float x0 = x[mg * 2 + 0];
    const float x1 = x[mg * 2 + 1];
    float lg[E_];
    float mx = -1e30f;
#pragma unroll
    for (int k = 0; k < E_; ++k) {
      lg[k] = x0 * gate_W[k] + x1 * gate_W[E_ + k] + gate_b[k];
      mx = fmaxf(mx, lg[k]);
    }
    float s = 0.0f;
#pragma unroll
    for (int k = 0; k < E_; ++k) s += __expf(lg[k] - mx);
    gate_s[tid] = __expf(lg[e] - mx) / s;
  }
  {
    const float w0a = W0[(e * 2 + 0) * H_ + tid];
    const float w1a = W0[(e * 2 + 1) * H_ + tid];
    const float bb  = b0[e * H_ + tid];
    for (int m = 0; m < MT; ++m) {
      const float x0 = x[(m0 + m) * 2 + 0];
      const float x1 = x[(m0 + m) * 2 + 1];
      const float z = OMEGA_ * fmaf(x1, w1a, fmaf(x0, w0a, bb));
      const float h = __sinf(z);
      __bf16 hi, lo; split_bf16(h, hi, lo);
      h_hi[m * HPAD + tid] = hi;
      h_lo[m * HPAD + tid] = lo;
    }
  }
  __syncthreads();

  const int nb0 = wave * 4;
#pragma unroll 1
  for (int l = 0; l < NHID_; ++l) {
    const float* WB = Wh + (size_t)(e * NHID_ + l) * (H_ * H_);
    f32x4 acc[4][4];
#pragma unroll
    for (int mt = 0; mt < 4; ++mt)
#pragma unroll
      for (int nbi = 0; nbi < 4; ++nbi)
        acc[mt][nbi] = (f32x4){0.f, 0.f, 0.f, 0.f};

#pragma unroll 2
    for (int kb = 0; kb < 8; ++kb) {
      const int k0 = kb * 32 + quad * 8;
      float bfv[4][8];
#pragma unroll
      for (int nbi = 0; nbi < 4; ++nbi) {
        const float* p = WB + (size_t)k0 * H_ + (nb0 + nbi) * 16 + l15;
#pragma unroll
        for (int j = 0; j < 8; ++j) bfv[nbi][j] = p[(size_t)j * H_];
      }
      bf16x8 ah[4], al[4];
#pragma unroll
      for (int mt = 0; mt < 4; ++mt) {
        ah[mt] = *reinterpret_cast<const bf16x8*>(&h_hi[(mt * 16 + l15) * HPAD + k0]);
        al[mt] = *reinterpret_cast<const bf16x8*>(&h_lo[(mt * 16 + l15) * HPAD + k0]);
      }
      bf16x8 bhf[4], blf[4];
#pragma unroll
      for (int nbi = 0; nbi < 4; ++nbi)
#pragma unroll
        for (int j = 0; j < 8; ++j) {
          __bf16 hi, lo; split_bf16(bfv[nbi][j], hi, lo);
          bhf[nbi][j] = hi; blf[nbi][j] = lo;
        }
#pragma unroll
      for (int mt = 0; mt < 4; ++mt)
#pragma unroll
        for (int nbi = 0; nbi < 4; ++nbi) {
          f32x4 a = acc[mt][nbi];
          a = __builtin_amdgcn_mfma_f32_16x16x32_bf16(al[mt], bhf[nbi], a, 0, 0, 0);
          a = __builtin_amdgcn_mfma_f32_16x16x32_bf16(ah[mt], blf[nbi], a, 0, 0, 0);
          a = __builtin_amdgcn_mfma_f32_16x16x32_bf16(ah[mt], bhf[nbi], a, 0, 0, 0);
          acc[mt][nbi] = a;
        }
    }
    __syncthreads();

    const float* bhrow = bh + (size_t)(e * NHID_ + l) * H_;
#pragma unroll
    for (int nbi = 0; nbi < 4; ++nbi) {
      const int n = (nb0 + nbi) * 16 + l15;
      const float bias = bhrow[n];
#pragma unroll
      for (int mt = 0; mt < 4; ++mt) {
        const int rbase = mt * 16 + quad * 4;
#pragma unroll
        for (int i = 0; i < 4; ++i) {
          const float z = OMEGA_ * (acc[mt][nbi][i] + bias);
          const float h = __sinf(z);
          __bf16 hi, lo; split_bf16(h, hi, lo);
          h_hi[(rbase + i) * HPAD + n] = hi;
          h_lo[(rbase + i) * HPAD + n] = lo;
        }
      }
    }
    __syncthreads();
  }

  {
    const float* WO = Wout + (size_t)e * (H_ * 3);
    f32x4 acco = (f32x4){0.f, 0.f, 0.f, 0.f};
    const int arow = wave * 16 + l15;
#pragma unroll
    for (int kb = 0; kb < 8; ++kb) {
      const int k0 = kb * 32 + quad * 8;
      float bfv[8];
#pragma unroll
      for (int j = 0; j < 8; ++j)
        bfv[j] = (l15 < 3) ? WO[(size_t)(k0 + j) * 3 + l15] : 0.0f;
      bf16x8 ah = *reinterpret_cast<const bf16x8*>(&h_hi[arow * HPAD + k0]);
      bf16x8 al = *reinterpret_cast<const bf16x8*>(&h_lo[arow * HPAD + k0]);
      bf16x8 bhf, blf;
#pragma unroll
      for (int j = 0; j < 8; ++j) {
        __bf16 hi, lo; split_bf16(bfv[j], hi, lo);
        bhf[j] = hi; blf[j] = lo;
      }
      acco = __builtin_amdgcn_mfma_f32_16x16x32_bf16(al, bhf, acco, 0, 0, 0);
      acco = __builtin_amdgcn_mfma_f32_16x16x32_bf16(ah, blf, acco, 0, 0, 0);
      acco = __builtin_amdgcn_mfma_f32_16x16x32_bf16(ah, bhf, acco, 0, 0, 0);
    }
    if (l15 < 3) {
      const float bo = bout[e * 3 + l15];
      const int rb = wave * 16 + quad * 4;
#pragma unroll
      for (int i = 0; i < 4; ++i) {
        const int m = rb + i;
        const float val = gate_s[m] * (acco[i] + bo);
        atomicAdd(&out[(size_t)(m0 + m) * 3 + l15], val);
      }
    }
  }
}

extern "C" void kernel_launch(void* const* d_in, const int* in_sizes, int n_in,
                              void* d_out, int out_size, void* d_ws, size_t ws_size,
                              hipStream_t stream) {
  const float* x     = (const float*)d_in[0];
  const float* gateW = (const float*)d_in[1];
  const float* gateb = (const float*)d_in[2];
  const float* W0    = (const float*)d_in[3];
  const float* b0    = (const float*)d_in[4];
  const float* Wh    = (const float*)d_in[5];
  const float* bh    = (const float*)d_in[6];
  const float* Wout  = (const float*)d_in[7];
  const float* bout  = (const float*)d_in[8];
  float* out = (float*)d_out;

  hipLaunchKernelGGL(zero_out_k, dim3(N_ * 3 / 256), dim3(256), 0, stream, out);

  if (ws_size >= WS_NEEDED) {
    __bf16* Pwh_hi = (__bf16*)d_ws;
    __bf16* Pwo_hi = (__bf16*)((char*)d_ws + (size_t)PWH_ELEMS * 2);
    __bf16* Pwo_lo = (__bf16*)((char*)d_ws + (size_t)PWH_ELEMS * 2 + (size_t)PWO_ELEMS * 2);
    hipLaunchKernelGGL(pack_wh_k,  dim3(768), dim3(256), 0, stream, Wh, Pwh_hi);
    hipLaunchKernelGGL(pack_wout_k, dim3(16), dim3(256), 0, stream, Wout, Pwo_hi, Pwo_lo);
    hipLaunchKernelGGL(moe_main_packed_k, dim3(N_ / MT, E_), dim3(256), 0, stream,
                       x, gateW, gateb, W0, b0, Pwh_hi, bh, Pwo_hi, Pwo_lo, bout, out);
  } else {
    hipLaunchKernelGGL(moe_main_direct_k, dim3(N_ / MT, E_), dim3(256), 0, stream,
                       x, gateW, gateb, W0, b0, Wh, bh, Wout, bout, out);
  }
}

// Round 3
// 284.094 us; speedup vs baseline: 1.1599x; 1.1221x over previous
//
#include <hip/hip_runtime.h>
#include <math.h>

#define E_ 8
#define H_ 256
#define N_ 65536
#define NHID_ 3
#define MT 64          // tile: N/64 = 1024 exact
#define HPAD 264       // LDS row stride (bf16 elems): row stride 528B
#define OMEGA_ 30.0f
#define REV_SCALE 4.7746482927568605f   // OMEGA/(2*pi): sin(OMEGA*z) = sin(2pi*(REV_SCALE*z))

// R21: revert to R18's proven structure (16x16x32 hidden GEMMs, per-expert grid,
// 97% MfmaUtil+VALUBusy packing, 231us) — R19/R20 showed the 32x32x16 switch loses
// ~35us to dependency stalls (4 indep MFMA chains/kb vs 16) regardless of grid shape.
// New levers on top of R18:
//   1. DROP v_fract before v_sin: |z_rev| <= 8.2 revolutions (bound: 256*wlim+1/16
//      -> 1.37, x4.775; first layer 1.71 x4.775), far inside v_sin's +-256 domain.
//      Saves 1 VALU op per activation element ~= 22us of the 120us VALU term.
//   2. Single-plane Wh pack kept from R19 (lo plane never read on hot path).
//   3. zero_out + pack_wh + pack_wout fused into one prep kernel (768x256 threads
//      = exactly N*3 for the zeroing) — 2 fewer launches.
// ws layout: Pwh_hi | Pwo_hi | Pwo_lo
#define PWH_ELEMS (E_ * NHID_ * 8 * 16 * 64 * 8)   // 1572864 bf16 = 3145728 B
#define PWO_ELEMS (E_ * 8 * 64 * 8)                // 32768 bf16 = 65536 B
#define WS_NEEDED ((size_t)PWH_ELEMS * 2 + 2 * (size_t)PWO_ELEMS * 2)  // 3276800 B

typedef __attribute__((ext_vector_type(8))) __bf16 bf16x8;
typedef __attribute__((ext_vector_type(4))) float f32x4;

// RNE split (pack + fallback path)
__device__ __forceinline__ void split_bf16(float v, __bf16& hi, __bf16& lo) {
  hi = (__bf16)v;
  lo = (__bf16)(v - (float)hi);
}

// hot-path: sin + RNE-bf16 + single LDS store. NO fract: inputs bounded |z|<=8.2
// revolutions, inside v_sin_f32's valid +-256 range (HW reduces internally).
__device__ __forceinline__ void sin_store(float z_rev, __bf16* h_hi, int idx) {
  const float s = __builtin_amdgcn_sinf(z_rev);   // sin(2*pi*z_rev)
  h_hi[idx] = (__bf16)s;   // RNE
}

// ---- zero d_out (fallback path only) ----
__global__ void zero_out_k(float* __restrict__ out) {
  out[blockIdx.x * 256 + threadIdx.x] = 0.0f;   // grid exactly N_*3/256
}

// ---- fused prep: zero out + pack Wh*REV_SCALE (hi only) + pack Wout (hi/lo) ----
// grid 768 x 256 = 196608 threads = N_*3 exactly (zeroing) = Wh frag count.
// Wh 16x16x32 B-frag order: value(t,j) = REV*Wh[el][kb*32+quad*8+j][nb*16+l15]
__global__ void prep_k(const float* __restrict__ Wh,
                       const float* __restrict__ Wout,
                       __bf16* __restrict__ Pwh,
                       __bf16* __restrict__ Pwo_hi,
                       __bf16* __restrict__ Pwo_lo,
                       float* __restrict__ out) {
  const int t = blockIdx.x * 256 + threadIdx.x;
  out[t] = 0.0f;                                  // N_*3 == 196608 == grid*block
  const int lane = t & 63;
  const int r = t >> 6;            // [0, 3072)
  const int nb = r & 15;
  const int kb = (r >> 4) & 7;
  const int el = r >> 7;           // [0, 24) = e*3+l
  const int n  = nb * 16 + (lane & 15);
  const int k0 = kb * 32 + (lane >> 4) * 8;
  const float* src = Wh + (size_t)el * (H_ * H_);
  __bf16* dhi = Pwh + (size_t)t * 8;
#pragma unroll
  for (int j = 0; j < 8; ++j)
    dhi[j] = (__bf16)(src[(size_t)(k0 + j) * H_ + n] * REV_SCALE);

  // Wout pack (UNscaled — final layer linear), 16x16x32 layout, t < 4096
  if (t < E_ * 8 * 64) {
    const int kb2 = (t >> 6) & 7;
    const int e   = t >> 9;
    const int n2  = lane & 15;
    const int k02 = kb2 * 32 + (lane >> 4) * 8;
    __bf16* dh = Pwo_hi + (size_t)t * 8;
    __bf16* dl = Pwo_lo + (size_t)t * 8;
#pragma unroll
    for (int j = 0; j < 8; ++j) {
      float v = (n2 < 3) ? Wout[((size_t)e * H_ + (k02 + j)) * 3 + n2] : 0.0f;
      __bf16 hi, lo;
      split_bf16(v, hi, lo);
      dh[j] = hi; dl[j] = lo;
    }
  }
}

// ---- fused MoE-SIREN, PACKED path, MT=64, single-MFMA hidden layers ----
// R18 structure exactly (best verified: 231us, MfmaUtil+VALUBusy=97%), minus fract.
__global__ __launch_bounds__(256, 4) void moe_main_packed_k(
    const float* __restrict__ x,
    const float* __restrict__ gate_W,
    const float* __restrict__ gate_b,
    const float* __restrict__ W0,
    const float* __restrict__ b0,
    const __bf16* __restrict__ Pwh_hi,
    const float* __restrict__ bh,
    const __bf16* __restrict__ Pwo_hi,
    const __bf16* __restrict__ Pwo_lo,
    const float* __restrict__ bout,
    float* __restrict__ out)
{
  __shared__ alignas(16) __bf16 h_hi[MT * HPAD];   // 33792 B
  __shared__ float gate_s[MT];                     // total ~34 KB -> 4 blocks/CU

  const int e    = blockIdx.y;
  const int m0   = blockIdx.x * MT;
  const int tid  = threadIdx.x;
  const int wave = tid >> 6;
  const int lane = tid & 63;
  const int l15  = lane & 15;
  const int quad = lane >> 4;

  // gate for this expert, one row per thread (fp32, matches jax softmax)
  if (tid < MT) {
    const int mg = m0 + tid;
    const float x0 = x[mg * 2 + 0];
    const float x1 = x[mg * 2 + 1];
    float lg[E_];
    float mx = -1e30f;
#pragma unroll
    for (int k = 0; k < E_; ++k) {
      lg[k] = x0 * gate_W[k] + x1 * gate_W[E_ + k] + gate_b[k];
      mx = fmaxf(mx, lg[k]);
    }
    float s = 0.0f;
#pragma unroll
    for (int k = 0; k < E_; ++k) s += __expf(lg[k] - mx);
    gate_s[tid] = __expf(lg[e] - mx) / s;
  }

  // first sine layer fp32, omega/2pi folded; thread tid owns column n=tid, all 64 rows
  {
    const float w0a = W0[(e * 2 + 0) * H_ + tid] * REV_SCALE;
    const float w1a = W0[(e * 2 + 1) * H_ + tid] * REV_SCALE;
    const float bb  = b0[e * H_ + tid] * REV_SCALE;
    for (int m = 0; m < MT; ++m) {
      const float x0 = x[(m0 + m) * 2 + 0];
      const float x1 = x[(m0 + m) * 2 + 1];
      const float z_rev = fmaf(x1, w1a, fmaf(x0, w0a, bb));
      sin_store(z_rev, h_hi, m * HPAD + tid);
    }
  }
  __syncthreads();

  const int nb0 = wave * 4;
  const size_t fragoff = (size_t)(nb0 * 64 + lane) * 8;   // wave-invariant frag offset

#pragma unroll 1
  for (int l = 0; l < NHID_; ++l) {
    const size_t lbase = (size_t)(e * NHID_ + l) * (8 * 16 * 64 * 8);
    const __bf16* pBh = Pwh_hi + lbase + fragoff;
    const float* bhrow = bh + (size_t)(e * NHID_ + l) * H_;

    // bias folded into acc init (C/D col = lane-only -> one bias per nbi, all 16 regs)
    float bias_rev[4];
#pragma unroll
    for (int nbi = 0; nbi < 4; ++nbi)
      bias_rev[nbi] = bhrow[(nb0 + nbi) * 16 + l15] * REV_SCALE;

    f32x4 acc[4][4];
#pragma unroll
    for (int mt = 0; mt < 4; ++mt)
#pragma unroll
      for (int nbi = 0; nbi < 4; ++nbi)
        acc[mt][nbi] = (f32x4){bias_rev[nbi], bias_rev[nbi], bias_rev[nbi], bias_rev[nbi]};

#pragma unroll 1          // ONE kb in flight: VGPR discipline
    for (int kb = 0; kb < 8; ++kb) {
      bf16x8 bhf[4];
#pragma unroll
      for (int nbi = 0; nbi < 4; ++nbi)
        bhf[nbi] = *reinterpret_cast<const bf16x8*>(pBh + nbi * 512);
      pBh += 16 * 64 * 8;   // 8192 elems per kb
      const int k0 = kb * 32 + quad * 8;
      bf16x8 ah[4];
#pragma unroll
      for (int mt = 0; mt < 4; ++mt)
        ah[mt] = *reinterpret_cast<const bf16x8*>(&h_hi[(mt * 16 + l15) * HPAD + k0]);
#pragma unroll
      for (int mt = 0; mt < 4; ++mt)
#pragma unroll
        for (int nbi = 0; nbi < 4; ++nbi)
          acc[mt][nbi] = __builtin_amdgcn_mfma_f32_16x16x32_bf16(
              ah[mt], bhf[nbi], acc[mt][nbi], 0, 0, 0);
    }
    __syncthreads();

#pragma unroll
    for (int nbi = 0; nbi < 4; ++nbi) {
      const int n = (nb0 + nbi) * 16 + l15;
#pragma unroll
      for (int mt = 0; mt < 4; ++mt) {
        const int rbase = mt * 16 + quad * 4;
#pragma unroll
        for (int i = 0; i < 4; ++i)
          sin_store(acc[mt][nbi][i], h_hi, (rbase + i) * HPAD + n);
      }
    }
    __syncthreads();
  }

  // output layer (linear): 2-term kept (only 16 MFMAs/wave — free accuracy)
  {
    const __bf16* pOh = Pwo_hi + (size_t)e * (8 * 64 * 8) + (size_t)lane * 8;
    const __bf16* pOl = Pwo_lo + (size_t)e * (8 * 64 * 8) + (size_t)lane * 8;
    f32x4 acco = (f32x4){0.f, 0.f, 0.f, 0.f};
    const int arow = wave * 16 + l15;
#pragma unroll 1
    for (int kb = 0; kb < 8; ++kb) {
      bf16x8 bhf = *reinterpret_cast<const bf16x8*>(pOh);
      bf16x8 blf = *reinterpret_cast<const bf16x8*>(pOl);
      pOh += 512; pOl += 512;
      const int k0 = kb * 32 + quad * 8;
      bf16x8 ah = *reinterpret_cast<const bf16x8*>(&h_hi[arow * HPAD + k0]);
      acco = __builtin_amdgcn_mfma_f32_16x16x32_bf16(ah, blf, acco, 0, 0, 0);
      acco = __builtin_amdgcn_mfma_f32_16x16x32_bf16(ah, bhf, acco, 0, 0, 0);
    }
    if (l15 < 3) {
      const float bo = bout[e * 3 + l15];
      const int rb = wave * 16 + quad * 4;
#pragma unroll
      for (int i = 0; i < 4; ++i) {
        const int m = rb + i;
        const float val = gate_s[m] * (acco[i] + bo);
        atomicAdd(&out[(size_t)(m0 + m) * 3 + l15], val);
      }
    }
  }
}

// ---- fallback: direct fp32-weight path (HW-verified round 3, MT=64, 3-term) ----
__global__ __launch_bounds__(256) void moe_main_direct_k(
    const float* __restrict__ x,
    const float* __restrict__ gate_W,
    const float* __restrict__ gate_b,
    const float* __restrict__ W0,
    const float* __restrict__ b0,
    const float* __restrict__ Wh,
    const float* __restrict__ bh,
    const float* __restrict__ Wout,
    const float* __restrict__ bout,
    float* __restrict__ out)
{
  __shared__ alignas(16) __bf16 h_hi[MT * HPAD];
  __shared__ alignas(16) __bf16 h_lo[MT * HPAD];
  __shared__ float gate_s[MT];

  const int e    = blockIdx.y;
  const int m0   = blockIdx.x * MT;
  const int tid  = threadIdx.x;
  const int wave = tid >> 6;
  const int lane = tid & 63;
  const int l15  = lane & 15;
  const int quad = lane >> 4;

  if (tid < MT) {
    const int mg = m0 + tid;
    const float x0 = x[mg * 2 + 0];
    const float x1 = x[mg * 2 + 1];
    float lg[E_];
    float mx = -1e30f;
#pragma unroll
    for (int k = 0; k < E_; ++k) {
      lg[k] = x0 * gate_W[k] + x1 * gate_W[E_ + k] + gate_b[k];
      mx = fmaxf(mx, lg[k]);
    }
    float s = 0.0f;
#pragma unroll
    for (int k = 0; k < E_; ++k) s += __expf(lg[k] - mx);
    gate_s[tid] = __expf(lg[e] - mx) / s;
  }
  {
    const float w0a = W0[(e * 2 + 0) * H_ + tid];
    const float w1a = W0[(e * 2 + 1) * H_ + tid];
    const float bb  = b0[e * H_ + tid];
    for (int m = 0; m < MT; ++m) {
      const float x0 = x[(m0 + m) * 2 + 0];
      const float x1 = x[(m0 + m) * 2 + 1];
      const float z = OMEGA_ * fmaf(x1, w1a, fmaf(x0, w0a, bb));
      const float h = __sinf(z);
      __bf16 hi, lo; split_bf16(h, hi, lo);
      h_hi[m * HPAD + tid] = hi;
      h_lo[m * HPAD + tid] = lo;
    }
  }
  __syncthreads();

  const int nb0 = wave * 4;
#pragma unroll 1
  for (int l = 0; l < NHID_; ++l) {
    const float* WB = Wh + (size_t)(e * NHID_ + l) * (H_ * H_);
    f32x4 acc[4][4];
#pragma unroll
    for (int mt = 0; mt < 4; ++mt)
#pragma unroll
      for (int nbi = 0; nbi < 4; ++nbi)
        acc[mt][nbi] = (f32x4){0.f, 0.f, 0.f, 0.f};

#pragma unroll 2
    for (int kb = 0; kb < 8; ++kb) {
      const int k0 = kb * 32 + quad * 8;
      float bfv[4][8];
#pragma unroll
      for (int nbi = 0; nbi < 4; ++nbi) {
        const float* p = WB + (size_t)k0 * H_ + (nb0 + nbi) * 16 + l15;
#pragma unroll
        for (int j = 0; j < 8; ++j) bfv[nbi][j] = p[(size_t)j * H_];
      }
      bf16x8 ah[4], al[4];
#pragma unroll
      for (int mt = 0; mt < 4; ++mt) {
        ah[mt] = *reinterpret_cast<const bf16x8*>(&h_hi[(mt * 16 + l15) * HPAD + k0]);
        al[mt] = *reinterpret_cast<const bf16x8*>(&h_lo[(mt * 16 + l15) * HPAD + k0]);
      }
      bf16x8 bhf[4], blf[4];
#pragma unroll
      for (int nbi = 0; nbi < 4; ++nbi)
#pragma unroll
        for (int j = 0; j < 8; ++j) {
          __bf16 hi, lo; split_bf16(bfv[nbi][j], hi, lo);
          bhf[nbi][j] = hi; blf[nbi][j] = lo;
        }
#pragma unroll
      for (int mt = 0; mt < 4; ++mt)
#pragma unroll
        for (int nbi = 0; nbi < 4; ++nbi) {
          f32x4 a = acc[mt][nbi];
          a = __builtin_amdgcn_mfma_f32_16x16x32_bf16(al[mt], bhf[nbi], a, 0, 0, 0);
          a = __builtin_amdgcn_mfma_f32_16x16x32_bf16(ah[mt], blf[nbi], a, 0, 0, 0);
          a = __builtin_amdgcn_mfma_f32_16x16x32_bf16(ah[mt], bhf[nbi], a, 0, 0, 0);
          acc[mt][nbi] = a;
        }
    }
    __syncthreads();

    const float* bhrow = bh + (size_t)(e * NHID_ + l) * H_;
#pragma unroll
    for (int nbi = 0; nbi < 4; ++nbi) {
      const int n = (nb0 + nbi) * 16 + l15;
      const float bias = bhrow[n];
#pragma unroll
      for (int mt = 0; mt < 4; ++mt) {
        const int rbase = mt * 16 + quad * 4;
#pragma unroll
        for (int i = 0; i < 4; ++i) {
          const float z = OMEGA_ * (acc[mt][nbi][i] + bias);
          const float h = __sinf(z);
          __bf16 hi, lo; split_bf16(h, hi, lo);
          h_hi[(rbase + i) * HPAD + n] = hi;
          h_lo[(rbase + i) * HPAD + n] = lo;
        }
      }
    }
    __syncthreads();
  }

  {
    const float* WO = Wout + (size_t)e * (H_ * 3);
    f32x4 acco = (f32x4){0.f, 0.f, 0.f, 0.f};
    const int arow = wave * 16 + l15;
#pragma unroll
    for (int kb = 0; kb < 8; ++kb) {
      const int k0 = kb * 32 + quad * 8;
      float bfv[8];
#pragma unroll
      for (int j = 0; j < 8; ++j)
        bfv[j] = (l15 < 3) ? WO[(size_t)(k0 + j) * 3 + l15] : 0.0f;
      bf16x8 ah = *reinterpret_cast<const bf16x8*>(&h_hi[arow * HPAD + k0]);
      bf16x8 al = *reinterpret_cast<const bf16x8*>(&h_lo[arow * HPAD + k0]);
      bf16x8 bhf, blf;
#pragma unroll
      for (int j = 0; j < 8; ++j) {
        __bf16 hi, lo; split_bf16(bfv[j], hi, lo);
        bhf[j] = hi; blf[j] = lo;
      }
      acco = __builtin_amdgcn_mfma_f32_16x16x32_bf16(al, bhf, acco, 0, 0, 0);
      acco = __builtin_amdgcn_mfma_f32_16x16x32_bf16(ah, blf, acco, 0, 0, 0);
      acco = __builtin_amdgcn_mfma_f32_16x16x32_bf16(ah, bhf, acco, 0, 0, 0);
    }
    if (l15 < 3) {
      const float bo = bout[e * 3 + l15];
      const int rb = wave * 16 + quad * 4;
#pragma unroll
      for (int i = 0; i < 4; ++i) {
        const int m = rb + i;
        const float val = gate_s[m] * (acco[i] + bo);
        atomicAdd(&out[(size_t)(m0 + m) * 3 + l15], val);
      }
    }
  }
}

extern "C" void kernel_launch(void* const* d_in, const int* in_sizes, int n_in,
                              void* d_out, int out_size, void* d_ws, size_t ws_size,
                              hipStream_t stream) {
  const float* x     = (const float*)d_in[0];
  const float* gateW = (const float*)d_in[1];
  const float* gateb = (const float*)d_in[2];
  const float* W0    = (const float*)d_in[3];
  const float* b0    = (const float*)d_in[4];
  const float* Wh    = (const float*)d_in[5];
  const float* bh    = (const float*)d_in[6];
  const float* Wout  = (const float*)d_in[7];
  const float* bout  = (const float*)d_in[8];
  float* out = (float*)d_out;

  if (ws_size >= WS_NEEDED) {
    __bf16* Pwh_hi = (__bf16*)d_ws;
    __bf16* Pwo_hi = (__bf16*)((char*)d_ws + (size_t)PWH_ELEMS * 2);
    __bf16* Pwo_lo = (__bf16*)((char*)d_ws + (size_t)PWH_ELEMS * 2 + (size_t)PWO_ELEMS * 2);
    hipLaunchKernelGGL(prep_k, dim3(768), dim3(256), 0, stream,
                       Wh, Wout, Pwh_hi, Pwo_hi, Pwo_lo, out);
    hipLaunchKernelGGL(moe_main_packed_k, dim3(N_ / MT, E_), dim3(256), 0, stream,
                       x, gateW, gateb, W0, b0, Pwh_hi, bh, Pwo_hi, Pwo_lo, bout, out);
  } else {
    hipLaunchKernelGGL(zero_out_k, dim3(N_ * 3 / 256), dim3(256), 0, stream, out);
    hipLaunchKernelGGL(moe_main_direct_k, dim3(N_ / MT, E_), dim3(256), 0, stream,
                       x, gateW, gateb, W0, b0, Wh, bh, Wout, bout, out);
  }
}